// Round 1
// baseline (295.811 us; speedup 1.0000x reference)
//
#include <hip/hip_runtime.h>
#include <hip/hip_bf16.h>
#include <stdint.h>

// Problem constants (from reference)
#define N_TOKENS   4096
#define IN_FEAT    1024
#define OUT_FEAT   2048
#define NUM_EXPERT 16

// GEMM tiling
#define BM 128
#define BN 128
#define BK 32
#define MAX_TILES 48          // sum_e ceil(cnt_e/128) <= 47
#define MAX_ROWS  6144        // padded sorted rows upper bound (<=6016)

typedef __bf16 bf16x8 __attribute__((ext_vector_type(8)));
typedef float  f32x4  __attribute__((ext_vector_type(4)));

__device__ __forceinline__ unsigned short f32_to_bf16_rne(float f) {
  union { float f; uint32_t u; } v; v.f = f;
  uint32_t u = v.u;
  u += 0x7fffu + ((u >> 16) & 1u);   // round-nearest-even
  return (unsigned short)(u >> 16);
}

// async global->LDS, 16B per lane. LDS dest must be wave-uniform base; lane i
// lands at base + i*16 (guide §5 caveat) — our flat tile layout matches.
__device__ __forceinline__ void async_copy16(const void* g, void* l) {
  __builtin_amdgcn_global_load_lds(
      (const __attribute__((address_space(1))) unsigned int*)g,
      (__attribute__((address_space(3))) unsigned int*)l, 16, 0, 0);
}

// ---------------------------------------------------------------------------
// Kernel 1: routing setup (single block). Histogram, padded prefix, scatter.
// ---------------------------------------------------------------------------
__global__ void k_setup(const int* __restrict__ gate,
                        int* __restrict__ pstart,     // [16] padded seg start
                        int* __restrict__ tile_e,     // [MAX_TILES]
                        int* __restrict__ tile_m,     // [MAX_TILES]
                        int* __restrict__ row_token)  // [MAX_ROWS], -1 = pad
{
  __shared__ int cnt[NUM_EXPERT];
  __shared__ int cur[NUM_EXPERT];
  __shared__ int ps[NUM_EXPERT];
  const int tid = threadIdx.x;
  if (tid < NUM_EXPERT) { cnt[tid] = 0; cur[tid] = 0; }
  __syncthreads();
  for (int b = tid; b < N_TOKENS; b += 256) atomicAdd(&cnt[gate[b]], 1);
  for (int r = tid; r < MAX_ROWS; r += 256) row_token[r] = -1;
  __syncthreads();
  if (tid == 0) {
    int p = 0, tot = 0;
    for (int e = 0; e < NUM_EXPERT; ++e) {
      ps[e] = p; pstart[e] = p;
      int nt = (cnt[e] + BM - 1) / BM;
      for (int t = 0; t < nt; ++t) { tile_e[tot] = e; tile_m[tot] = t; ++tot; }
      p += nt * BM;
    }
    for (int s = tot; s < MAX_TILES; ++s) { tile_e[s] = -1; tile_m[s] = 0; }
  }
  __syncthreads();
  for (int b = tid; b < N_TOKENS; b += 256) {
    int e = gate[b];
    int pos = atomicAdd(&cur[e], 1);
    row_token[ps[e] + pos] = b;
  }
}

// ---------------------------------------------------------------------------
// Kernel 2: weight fp32 -> bf16 (layout [E][O][I] kept: already B^T / NT form)
// 33,554,432 elems = 4096 blocks * 256 threads * 8 float4
// ---------------------------------------------------------------------------
__global__ void k_cast_w(const float4* __restrict__ w, ushort4* __restrict__ wb) {
  const int base = blockIdx.x * 256 + threadIdx.x;
#pragma unroll
  for (int i = 0; i < 8; ++i) {
    int v = base + i * 1048576;       // 4096*256
    float4 f = w[v];
    ushort4 o;
    o.x = f32_to_bf16_rne(f.x); o.y = f32_to_bf16_rne(f.y);
    o.z = f32_to_bf16_rne(f.z); o.w = f32_to_bf16_rne(f.w);
    wb[v] = o;
  }
}

// ---------------------------------------------------------------------------
// Kernel 3: gather x into sorted padded order + cast to bf16; pads -> zeros.
// One block per padded row; 256 threads * 4 floats = 1024 = IN_FEAT.
// ---------------------------------------------------------------------------
__global__ void k_gather_x(const float4* __restrict__ x,
                           const int* __restrict__ row_token,
                           ushort4* __restrict__ xs) {
  const int r = blockIdx.x;
  const int tok = row_token[r];
  const int c = threadIdx.x;
  ushort4 o;
  if (tok >= 0) {
    float4 f = x[tok * 256 + c];
    o.x = f32_to_bf16_rne(f.x); o.y = f32_to_bf16_rne(f.y);
    o.z = f32_to_bf16_rne(f.z); o.w = f32_to_bf16_rne(f.w);
  } else {
    o.x = 0; o.y = 0; o.z = 0; o.w = 0;
  }
  xs[r * 256 + c] = o;
}

// ---------------------------------------------------------------------------
// Kernel 4: grouped GEMM. out[token, n] = sum_k xs[row, k] * w[e][n][k]
// 128x128 tile, 4 waves (2x2), each wave 4x4 of mfma_f32_16x16x32_bf16.
// Staging via global_load_lds width=16 (m97 structure).
// ---------------------------------------------------------------------------
__global__ void __launch_bounds__(256)
k_gemm(const unsigned short* __restrict__ xs,   // [MAX_ROWS][IN_FEAT] bf16
       const unsigned short* __restrict__ wb,   // [E][OUT_FEAT][IN_FEAT] bf16
       const int* __restrict__ pstart,
       const int* __restrict__ tile_e,
       const int* __restrict__ tile_m,
       const int* __restrict__ row_token,
       float* __restrict__ out) {
  __shared__ unsigned short As[BM * BK];   // 8 KB, [row][k] row-major
  __shared__ unsigned short Bs[BN * BK];   // 8 KB, [n][k] row-major
  __shared__ int rowtok_s[BM];

  const int slot = blockIdx.y;
  const int e = tile_e[slot];
  if (e < 0) return;
  const int seg0 = pstart[e] + tile_m[slot] * BM;
  const int n0 = blockIdx.x * BN;

  const int tid  = threadIdx.x;
  const int wid  = tid >> 6;
  const int lane = tid & 63;
  const int lr   = lane & 15;
  const int quad = lane >> 4;
  const int wm   = (wid >> 1) * 64;   // wave m-offset in tile
  const int wn   = (wid & 1) * 64;    // wave n-offset in tile

  if (tid < BM) rowtok_s[tid] = row_token[seg0 + tid];

  // staging: flat tile elem = it*2048 + tid*8 -> row = it*64 + tid/4, kk=(tid&3)*8
  const int srow = tid >> 2;
  const int skk  = (tid & 3) * 8;
  const unsigned short* ag = xs + (size_t)(seg0 + srow) * IN_FEAT + skk;
  const unsigned short* bg = wb + (size_t)e * OUT_FEAT * IN_FEAT
                                + (size_t)(n0 + srow) * IN_FEAT + skk;

  f32x4 acc[4][4];
  const f32x4 z = {0.f, 0.f, 0.f, 0.f};
#pragma unroll
  for (int i = 0; i < 4; ++i)
#pragma unroll
    for (int j = 0; j < 4; ++j) acc[i][j] = z;

  for (int k0 = 0; k0 < IN_FEAT; k0 += BK) {
    // A tile: rows seg0..seg0+127, cols k0..k0+31 (pads are zero rows in xs)
    async_copy16(ag + k0,               &As[wid * 512]);
    async_copy16(ag + 64 * IN_FEAT + k0, &As[2048 + wid * 512]);
    // B tile: rows n0..n0+127 of expert e
    async_copy16(bg + k0,               &Bs[wid * 512]);
    async_copy16(bg + 64 * IN_FEAT + k0, &Bs[2048 + wid * 512]);
    __syncthreads();   // compiler emits vmcnt(0) drain before s_barrier

    bf16x8 af[4], bf[4];
#pragma unroll
    for (int mi = 0; mi < 4; ++mi)
      af[mi] = *(const bf16x8*)&As[(wm + mi * 16 + lr) * BK + quad * 8];
#pragma unroll
    for (int ni = 0; ni < 4; ++ni)
      bf[ni] = *(const bf16x8*)&Bs[(wn + ni * 16 + lr) * BK + quad * 8];
#pragma unroll
    for (int mi = 0; mi < 4; ++mi)
#pragma unroll
      for (int ni = 0; ni < 4; ++ni)
        acc[mi][ni] = __builtin_amdgcn_mfma_f32_16x16x32_bf16(
            af[mi], bf[ni], acc[mi][ni], 0, 0, 0);
    __syncthreads();   // protect LDS before next stage overwrite
  }

  // Epilogue: C/D layout col=lane&15, row=quad*4+reg (verified m89/m91).
#pragma unroll
  for (int mi = 0; mi < 4; ++mi) {
    const int mb = wm + mi * 16 + quad * 4;
    const int t0 = rowtok_s[mb + 0];
    const int t1 = rowtok_s[mb + 1];
    const int t2 = rowtok_s[mb + 2];
    const int t3 = rowtok_s[mb + 3];
#pragma unroll
    for (int ni = 0; ni < 4; ++ni) {
      const int n = n0 + wn + ni * 16 + lr;
      f32x4 c = acc[mi][ni];
      if (t0 >= 0) out[(size_t)t0 * OUT_FEAT + n] = c[0];
      if (t1 >= 0) out[(size_t)t1 * OUT_FEAT + n] = c[1];
      if (t2 >= 0) out[(size_t)t2 * OUT_FEAT + n] = c[2];
      if (t3 >= 0) out[(size_t)t3 * OUT_FEAT + n] = c[3];
    }
  }
}

// ---------------------------------------------------------------------------
extern "C" void kernel_launch(void* const* d_in, const int* in_sizes, int n_in,
                              void* d_out, int out_size, void* d_ws, size_t ws_size,
                              hipStream_t stream) {
  const float* x    = (const float*)d_in[0];
  const int*   gate = (const int*)d_in[1];
  const float* w    = (const float*)d_in[2];
  float* out = (float*)d_out;

  // workspace layout (~80 MB)
  char* ws = (char*)d_ws;
  unsigned short* wb = (unsigned short*)ws;                        // 64 MB
  unsigned short* xs = (unsigned short*)(ws + 67108864);           // 12 MB
  int* row_token = (int*)(ws + 67108864 + 12582912);               // 24 KB
  int* pstart = row_token + MAX_ROWS;
  int* tile_e = pstart + NUM_EXPERT;
  int* tile_m = tile_e + MAX_TILES;

  k_setup<<<1, 256, 0, stream>>>(gate, pstart, tile_e, tile_m, row_token);
  k_cast_w<<<4096, 256, 0, stream>>>((const float4*)w, (ushort4*)wb);
  k_gather_x<<<MAX_ROWS, 256, 0, stream>>>((const float4*)x, row_token,
                                           (ushort4*)xs);
  dim3 g(OUT_FEAT / BN, MAX_TILES);
  k_gemm<<<g, 256, 0, stream>>>(xs, wb, pstart, tile_e, tile_m, row_token, out);
}

// Round 2
// 284.881 us; speedup vs baseline: 1.0384x; 1.0384x over previous
//
#include <hip/hip_runtime.h>
#include <hip/hip_bf16.h>
#include <stdint.h>

// Problem constants (from reference)
#define N_TOKENS   4096
#define IN_FEAT    1024
#define OUT_FEAT   2048
#define NUM_EXPERT 16

// GEMM tiling
#define BM 128
#define BN 128
#define BK 32
#define MAX_TILES 48          // sum_e ceil(cnt_e/128) <= 47
#define MAX_ROWS  6144        // padded sorted rows upper bound (<=6016)

typedef __bf16 bf16x8 __attribute__((ext_vector_type(8)));
typedef float  f32x4  __attribute__((ext_vector_type(4)));
typedef unsigned short us8 __attribute__((ext_vector_type(8)));  // 16B store

__device__ __forceinline__ unsigned short f32_to_bf16_rne(float f) {
  union { float f; uint32_t u; } v; v.f = f;
  uint32_t u = v.u;
  u += 0x7fffu + ((u >> 16) & 1u);   // round-nearest-even
  return (unsigned short)(u >> 16);
}

// async global->LDS, 16B per lane. LDS dest must be wave-uniform base; lane i
// lands at base + i*16 (guide §5 caveat) — our flat tile layout matches.
__device__ __forceinline__ void async_copy16(const void* g, void* l) {
  __builtin_amdgcn_global_load_lds(
      (const __attribute__((address_space(1))) unsigned int*)g,
      (__attribute__((address_space(3))) unsigned int*)l, 16, 0, 0);
}

// ---------------------------------------------------------------------------
// Kernel 1: routing setup (single block). Histogram, padded prefix, scatter.
// ---------------------------------------------------------------------------
__global__ void k_setup(const int* __restrict__ gate,
                        int* __restrict__ pstart,     // [16] padded seg start
                        int* __restrict__ tile_e,     // [MAX_TILES]
                        int* __restrict__ tile_m,     // [MAX_TILES]
                        int* __restrict__ row_token)  // [MAX_ROWS], -1 = pad
{
  __shared__ int cnt[NUM_EXPERT];
  __shared__ int cur[NUM_EXPERT];
  __shared__ int ps[NUM_EXPERT];
  const int tid = threadIdx.x;
  if (tid < NUM_EXPERT) { cnt[tid] = 0; cur[tid] = 0; }
  __syncthreads();
  for (int b = tid; b < N_TOKENS; b += 256) atomicAdd(&cnt[gate[b]], 1);
  for (int r = tid; r < MAX_ROWS; r += 256) row_token[r] = -1;
  __syncthreads();
  if (tid == 0) {
    int p = 0, tot = 0;
    for (int e = 0; e < NUM_EXPERT; ++e) {
      ps[e] = p; pstart[e] = p;
      int nt = (cnt[e] + BM - 1) / BM;
      for (int t = 0; t < nt; ++t) { tile_e[tot] = e; tile_m[tot] = t; ++tot; }
      p += nt * BM;
    }
    for (int s = tot; s < MAX_TILES; ++s) { tile_e[s] = -1; tile_m[s] = 0; }
  }
  __syncthreads();
  for (int b = tid; b < N_TOKENS; b += 256) {
    int e = gate[b];
    int pos = atomicAdd(&cur[e], 1);
    row_token[ps[e] + pos] = b;
  }
}

// ---------------------------------------------------------------------------
// Kernel 2: weight fp32 -> bf16, block-contiguous streaming.
// 8192 blocks * 256 threads; each thread: 2 iters * (2 float4 -> 1 ushort8).
// Block covers a contiguous 16 KB fp32 span -> HBM-friendly streaming; 16B
// coalesced stores (vs old 16MB-strided reads + 8B stores @ 1.7 TB/s).
// ---------------------------------------------------------------------------
__global__ void k_cast_w(const float4* __restrict__ w, us8* __restrict__ wb) {
#pragma unroll
  for (int i = 0; i < 2; ++i) {
    const int p = blockIdx.x * 512 + i * 256 + threadIdx.x;  // ushort8 index
    float4 a = w[2 * p];
    float4 b = w[2 * p + 1];
    us8 o;
    o[0] = f32_to_bf16_rne(a.x); o[1] = f32_to_bf16_rne(a.y);
    o[2] = f32_to_bf16_rne(a.z); o[3] = f32_to_bf16_rne(a.w);
    o[4] = f32_to_bf16_rne(b.x); o[5] = f32_to_bf16_rne(b.y);
    o[6] = f32_to_bf16_rne(b.z); o[7] = f32_to_bf16_rne(b.w);
    wb[p] = o;
  }
}

// ---------------------------------------------------------------------------
// Kernel 3: gather x into sorted padded order + cast to bf16; pads -> zeros.
// 2 rows per block; 128 threads/row; 16B stores.
// ---------------------------------------------------------------------------
__global__ void k_gather_x(const float4* __restrict__ x,
                           const int* __restrict__ row_token,
                           us8* __restrict__ xs) {
  const int r = blockIdx.x * 2 + (threadIdx.x >> 7);
  const int c = threadIdx.x & 127;
  const int tok = row_token[r];
  us8 o;
  if (tok >= 0) {
    float4 a = x[tok * 256 + c * 2];
    float4 b = x[tok * 256 + c * 2 + 1];
    o[0] = f32_to_bf16_rne(a.x); o[1] = f32_to_bf16_rne(a.y);
    o[2] = f32_to_bf16_rne(a.z); o[3] = f32_to_bf16_rne(a.w);
    o[4] = f32_to_bf16_rne(b.x); o[5] = f32_to_bf16_rne(b.y);
    o[6] = f32_to_bf16_rne(b.z); o[7] = f32_to_bf16_rne(b.w);
  } else {
    o = (us8)0;
  }
  xs[r * 128 + c] = o;
}

// ---------------------------------------------------------------------------
// Kernel 4: grouped GEMM. out[token, n] = sum_k xs[row, k] * w[e][n][k]
// 128x128 tile, 4 waves (2x2), each wave 4x4 of mfma_f32_16x16x32_bf16.
// Staging via global_load_lds width=16 (m97 structure).
// ---------------------------------------------------------------------------
__global__ void __launch_bounds__(256)
k_gemm(const unsigned short* __restrict__ xs,   // [MAX_ROWS][IN_FEAT] bf16
       const unsigned short* __restrict__ wb,   // [E][OUT_FEAT][IN_FEAT] bf16
       const int* __restrict__ pstart,
       const int* __restrict__ tile_e,
       const int* __restrict__ tile_m,
       const int* __restrict__ row_token,
       float* __restrict__ out) {
  __shared__ unsigned short As[BM * BK];   // 8 KB, [row][k] row-major
  __shared__ unsigned short Bs[BN * BK];   // 8 KB, [n][k] row-major
  __shared__ int rowtok_s[BM];

  const int slot = blockIdx.y;
  const int e = tile_e[slot];
  if (e < 0) return;
  const int seg0 = pstart[e] + tile_m[slot] * BM;
  const int n0 = blockIdx.x * BN;

  const int tid  = threadIdx.x;
  const int wid  = tid >> 6;
  const int lane = tid & 63;
  const int lr   = lane & 15;
  const int quad = lane >> 4;
  const int wm   = (wid >> 1) * 64;   // wave m-offset in tile
  const int wn   = (wid & 1) * 64;    // wave n-offset in tile

  if (tid < BM) rowtok_s[tid] = row_token[seg0 + tid];

  // staging: flat tile elem = it*2048 + tid*8 -> row = it*64 + tid/4, kk=(tid&3)*8
  const int srow = tid >> 2;
  const int skk  = (tid & 3) * 8;
  const unsigned short* ag = xs + (size_t)(seg0 + srow) * IN_FEAT + skk;
  const unsigned short* bg = wb + (size_t)e * OUT_FEAT * IN_FEAT
                                + (size_t)(n0 + srow) * IN_FEAT + skk;

  f32x4 acc[4][4];
  const f32x4 z = {0.f, 0.f, 0.f, 0.f};
#pragma unroll
  for (int i = 0; i < 4; ++i)
#pragma unroll
    for (int j = 0; j < 4; ++j) acc[i][j] = z;

  for (int k0 = 0; k0 < IN_FEAT; k0 += BK) {
    // A tile: rows seg0..seg0+127, cols k0..k0+31 (pads are zero rows in xs)
    async_copy16(ag + k0,                &As[wid * 512]);
    async_copy16(ag + 64 * IN_FEAT + k0, &As[2048 + wid * 512]);
    // B tile: rows n0..n0+127 of expert e
    async_copy16(bg + k0,                &Bs[wid * 512]);
    async_copy16(bg + 64 * IN_FEAT + k0, &Bs[2048 + wid * 512]);
    __syncthreads();   // compiler emits vmcnt(0) drain before s_barrier

    bf16x8 af[4], bf[4];
#pragma unroll
    for (int mi = 0; mi < 4; ++mi)
      af[mi] = *(const bf16x8*)&As[(wm + mi * 16 + lr) * BK + quad * 8];
#pragma unroll
    for (int ni = 0; ni < 4; ++ni)
      bf[ni] = *(const bf16x8*)&Bs[(wn + ni * 16 + lr) * BK + quad * 8];
#pragma unroll
    for (int mi = 0; mi < 4; ++mi)
#pragma unroll
      for (int ni = 0; ni < 4; ++ni)
        acc[mi][ni] = __builtin_amdgcn_mfma_f32_16x16x32_bf16(
            af[mi], bf[ni], acc[mi][ni], 0, 0, 0);
    __syncthreads();   // protect LDS before next stage overwrite
  }

  // Epilogue: C/D layout col=lane&15, row=quad*4+reg (verified m89/m91).
#pragma unroll
  for (int mi = 0; mi < 4; ++mi) {
    const int mb = wm + mi * 16 + quad * 4;
    const int t0 = rowtok_s[mb + 0];
    const int t1 = rowtok_s[mb + 1];
    const int t2 = rowtok_s[mb + 2];
    const int t3 = rowtok_s[mb + 3];
#pragma unroll
    for (int ni = 0; ni < 4; ++ni) {
      const int n = n0 + wn + ni * 16 + lr;
      f32x4 c = acc[mi][ni];
      if (t0 >= 0) out[(size_t)t0 * OUT_FEAT + n] = c[0];
      if (t1 >= 0) out[(size_t)t1 * OUT_FEAT + n] = c[1];
      if (t2 >= 0) out[(size_t)t2 * OUT_FEAT + n] = c[2];
      if (t3 >= 0) out[(size_t)t3 * OUT_FEAT + n] = c[3];
    }
  }
}

// ---------------------------------------------------------------------------
extern "C" void kernel_launch(void* const* d_in, const int* in_sizes, int n_in,
                              void* d_out, int out_size, void* d_ws, size_t ws_size,
                              hipStream_t stream) {
  const float* x    = (const float*)d_in[0];
  const int*   gate = (const int*)d_in[1];
  const float* w    = (const float*)d_in[2];
  float* out = (float*)d_out;

  // workspace layout (~80 MB)
  char* ws = (char*)d_ws;
  unsigned short* wb = (unsigned short*)ws;                        // 64 MB
  unsigned short* xs = (unsigned short*)(ws + 67108864);           // 12 MB
  int* row_token = (int*)(ws + 67108864 + 12582912);               // 24 KB
  int* pstart = row_token + MAX_ROWS;
  int* tile_e = pstart + NUM_EXPERT;
  int* tile_m = tile_e + MAX_TILES;

  k_setup<<<1, 256, 0, stream>>>(gate, pstart, tile_e, tile_m, row_token);
  k_cast_w<<<8192, 256, 0, stream>>>((const float4*)w, (us8*)wb);
  k_gather_x<<<MAX_ROWS / 2, 256, 0, stream>>>((const float4*)x, row_token,
                                               (us8*)xs);
  dim3 g(OUT_FEAT / BN, MAX_TILES);
  k_gemm<<<g, 256, 0, stream>>>(xs, wb, pstart, tile_e, tile_m, row_token, out);
}

// Round 3
// 271.101 us; speedup vs baseline: 1.0911x; 1.0508x over previous
//
#include <hip/hip_runtime.h>
#include <hip/hip_bf16.h>
#include <stdint.h>

// Problem constants (from reference)
#define N_TOKENS   4096
#define IN_FEAT    1024
#define OUT_FEAT   2048
#define NUM_EXPERT 16

// GEMM tiling
#define BM 128
#define BN 128
#define BK 32
#define MAX_TILES 48          // sum_e ceil(cnt_e/128) <= 47
#define MAX_ROWS  6144        // padded sorted rows upper bound (<=6016)

typedef __bf16 bf16x8 __attribute__((ext_vector_type(8)));
typedef float  f32x4  __attribute__((ext_vector_type(4)));
typedef unsigned short us8 __attribute__((ext_vector_type(8)));  // 16B

__device__ __forceinline__ unsigned short f32_to_bf16_rne(float f) {
  union { float f; uint32_t u; } v; v.f = f;
  uint32_t u = v.u;
  u += 0x7fffu + ((u >> 16) & 1u);   // round-nearest-even
  return (unsigned short)(u >> 16);
}

// async global->LDS, 16B per lane. LDS dest is wave-uniform base + lane*16.
__device__ __forceinline__ void async_copy16(const void* g, void* l) {
  __builtin_amdgcn_global_load_lds(
      (const __attribute__((address_space(1))) unsigned int*)g,
      (__attribute__((address_space(3))) unsigned int*)l, 16, 0, 0);
}

// ---------------------------------------------------------------------------
// Kernel 1: routing setup (single block). Histogram, padded prefix, scatter.
// ---------------------------------------------------------------------------
__global__ void k_setup(const int* __restrict__ gate,
                        int* __restrict__ pstart,     // [16] padded seg start
                        int* __restrict__ tile_e,     // [MAX_TILES]
                        int* __restrict__ tile_m,     // [MAX_TILES]
                        int* __restrict__ row_token)  // [MAX_ROWS], -1 = pad
{
  __shared__ int cnt[NUM_EXPERT];
  __shared__ int cur[NUM_EXPERT];
  __shared__ int ps[NUM_EXPERT];
  const int tid = threadIdx.x;
  if (tid < NUM_EXPERT) { cnt[tid] = 0; cur[tid] = 0; }
  __syncthreads();
  for (int b = tid; b < N_TOKENS; b += 256) atomicAdd(&cnt[gate[b]], 1);
  for (int r = tid; r < MAX_ROWS; r += 256) row_token[r] = -1;
  __syncthreads();
  if (tid == 0) {
    int p = 0, tot = 0;
    for (int e = 0; e < NUM_EXPERT; ++e) {
      ps[e] = p; pstart[e] = p;
      int nt = (cnt[e] + BM - 1) / BM;
      for (int t = 0; t < nt; ++t) { tile_e[tot] = e; tile_m[tot] = t; ++tot; }
      p += nt * BM;
    }
    for (int s = tot; s < MAX_TILES; ++s) { tile_e[s] = -1; tile_m[s] = 0; }
  }
  __syncthreads();
  for (int b = tid; b < N_TOKENS; b += 256) {
    int e = gate[b];
    int pos = atomicAdd(&cur[e], 1);
    row_token[ps[e] + pos] = b;
  }
}

// ---------------------------------------------------------------------------
// Kernel 2: gather x into sorted padded order + cast to bf16; pads -> zeros.
// 2 rows per block; 128 threads/row; 16B stores.
// ---------------------------------------------------------------------------
__global__ void k_gather_x(const float4* __restrict__ x,
                           const int* __restrict__ row_token,
                           us8* __restrict__ xs) {
  const int r = blockIdx.x * 2 + (threadIdx.x >> 7);
  const int c = threadIdx.x & 127;
  const int tok = row_token[r];
  us8 o;
  if (tok >= 0) {
    float4 a = x[tok * 256 + c * 2];
    float4 b = x[tok * 256 + c * 2 + 1];
    o[0] = f32_to_bf16_rne(a.x); o[1] = f32_to_bf16_rne(a.y);
    o[2] = f32_to_bf16_rne(a.z); o[3] = f32_to_bf16_rne(a.w);
    o[4] = f32_to_bf16_rne(b.x); o[5] = f32_to_bf16_rne(b.y);
    o[6] = f32_to_bf16_rne(b.z); o[7] = f32_to_bf16_rne(b.w);
  } else {
    o = (us8)0;
  }
  xs[r * 128 + c] = o;
}

// ---------------------------------------------------------------------------
// Kernel 3: grouped GEMM with FUSED weight fp32->bf16 conversion.
// out[token, n] = sum_k xs[row, k] * w_f32[e][n][k]
// 128x128 tile, 4 waves (2x2), each wave 4x4 of mfma_f32_16x16x32_bf16.
// A (activations): bf16 from xs via global_load_lds width=16.
// B (weights): fp32 global loads -> RNE convert -> ds_write_b128.
// ---------------------------------------------------------------------------
__global__ void __launch_bounds__(256)
k_gemm(const unsigned short* __restrict__ xs,   // [MAX_ROWS][IN_FEAT] bf16
       const float* __restrict__ w,             // [E][OUT_FEAT][IN_FEAT] fp32
       const int* __restrict__ pstart,
       const int* __restrict__ tile_e,
       const int* __restrict__ tile_m,
       const int* __restrict__ row_token,
       float* __restrict__ out) {
  __shared__ unsigned short As[BM * BK];   // 8 KB, [row][k] row-major
  __shared__ unsigned short Bs[BN * BK];   // 8 KB, [n][k] row-major
  __shared__ int rowtok_s[BM];

  const int slot = blockIdx.y;
  const int e = tile_e[slot];
  if (e < 0) return;
  const int seg0 = pstart[e] + tile_m[slot] * BM;
  const int n0 = blockIdx.x * BN;

  const int tid  = threadIdx.x;
  const int wid  = tid >> 6;
  const int lane = tid & 63;
  const int lr   = lane & 15;
  const int quad = lane >> 4;
  const int wm   = (wid >> 1) * 64;   // wave m-offset in tile
  const int wn   = (wid & 1) * 64;    // wave n-offset in tile

  if (tid < BM) rowtok_s[tid] = row_token[seg0 + tid];

  // A staging: flat elem = it*2048 + tid*8 -> row = tid/4, kk=(tid&3)*8
  const int srow = tid >> 2;
  const int skk  = (tid & 3) * 8;
  const unsigned short* ag = xs + (size_t)(seg0 + srow) * IN_FEAT + skk;

  // B staging: thread covers 16 consecutive fp32 of one weight row.
  const int brow = tid >> 1;          // 0..127 (n within tile)
  const int bk16 = (tid & 1) * 16;    // 0 or 16 (k within tile)
  const float* bg = w + (size_t)e * OUT_FEAT * IN_FEAT
                      + (size_t)(n0 + brow) * IN_FEAT + bk16;
  us8* bs0 = (us8*)&Bs[brow * BK + bk16];      // 16B-aligned
  us8* bs1 = (us8*)&Bs[brow * BK + bk16 + 8];

  f32x4 acc[4][4];
  const f32x4 z = {0.f, 0.f, 0.f, 0.f};
#pragma unroll
  for (int i = 0; i < 4; ++i)
#pragma unroll
    for (int j = 0; j < 4; ++j) acc[i][j] = z;

  for (int k0 = 0; k0 < IN_FEAT; k0 += BK) {
    // B: 64B fp32 per thread -> 16 bf16 -> 32B LDS
    const float4* bp = (const float4*)(bg + k0);
    float4 f0 = bp[0], f1 = bp[1], f2 = bp[2], f3 = bp[3];
    // A: async direct-to-LDS (pads are zero rows in xs)
    async_copy16(ag + k0,                &As[wid * 512]);
    async_copy16(ag + 64 * IN_FEAT + k0, &As[2048 + wid * 512]);
    us8 lo, hi;
    lo[0] = f32_to_bf16_rne(f0.x); lo[1] = f32_to_bf16_rne(f0.y);
    lo[2] = f32_to_bf16_rne(f0.z); lo[3] = f32_to_bf16_rne(f0.w);
    lo[4] = f32_to_bf16_rne(f1.x); lo[5] = f32_to_bf16_rne(f1.y);
    lo[6] = f32_to_bf16_rne(f1.z); lo[7] = f32_to_bf16_rne(f1.w);
    hi[0] = f32_to_bf16_rne(f2.x); hi[1] = f32_to_bf16_rne(f2.y);
    hi[2] = f32_to_bf16_rne(f2.z); hi[3] = f32_to_bf16_rne(f2.w);
    hi[4] = f32_to_bf16_rne(f3.x); hi[5] = f32_to_bf16_rne(f3.y);
    hi[6] = f32_to_bf16_rne(f3.z); hi[7] = f32_to_bf16_rne(f3.w);
    *bs0 = lo;
    *bs1 = hi;
    __syncthreads();   // drains vmcnt (async A) + lgkm (B writes)

    bf16x8 af[4], bf[4];
#pragma unroll
    for (int mi = 0; mi < 4; ++mi)
      af[mi] = *(const bf16x8*)&As[(wm + mi * 16 + lr) * BK + quad * 8];
#pragma unroll
    for (int ni = 0; ni < 4; ++ni)
      bf[ni] = *(const bf16x8*)&Bs[(wn + ni * 16 + lr) * BK + quad * 8];
#pragma unroll
    for (int mi = 0; mi < 4; ++mi)
#pragma unroll
      for (int ni = 0; ni < 4; ++ni)
        acc[mi][ni] = __builtin_amdgcn_mfma_f32_16x16x32_bf16(
            af[mi], bf[ni], acc[mi][ni], 0, 0, 0);
    __syncthreads();   // protect LDS before next stage overwrite
  }

  // Epilogue: C/D layout col=lane&15, row=quad*4+reg (verified m89/m91).
#pragma unroll
  for (int mi = 0; mi < 4; ++mi) {
    const int mb = wm + mi * 16 + quad * 4;
    const int t0 = rowtok_s[mb + 0];
    const int t1 = rowtok_s[mb + 1];
    const int t2 = rowtok_s[mb + 2];
    const int t3 = rowtok_s[mb + 3];
#pragma unroll
    for (int ni = 0; ni < 4; ++ni) {
      const int n = n0 + wn + ni * 16 + lr;
      f32x4 c = acc[mi][ni];
      if (t0 >= 0) out[(size_t)t0 * OUT_FEAT + n] = c[0];
      if (t1 >= 0) out[(size_t)t1 * OUT_FEAT + n] = c[1];
      if (t2 >= 0) out[(size_t)t2 * OUT_FEAT + n] = c[2];
      if (t3 >= 0) out[(size_t)t3 * OUT_FEAT + n] = c[3];
    }
  }
}

// ---------------------------------------------------------------------------
extern "C" void kernel_launch(void* const* d_in, const int* in_sizes, int n_in,
                              void* d_out, int out_size, void* d_ws, size_t ws_size,
                              hipStream_t stream) {
  const float* x    = (const float*)d_in[0];
  const int*   gate = (const int*)d_in[1];
  const float* w    = (const float*)d_in[2];
  float* out = (float*)d_out;

  // workspace layout (~13 MB)
  char* ws = (char*)d_ws;
  unsigned short* xs = (unsigned short*)ws;                        // 12 MB
  int* row_token = (int*)(ws + 12582912);                          // 24 KB
  int* pstart = row_token + MAX_ROWS;
  int* tile_e = pstart + NUM_EXPERT;
  int* tile_m = tile_e + MAX_TILES;

  k_setup<<<1, 256, 0, stream>>>(gate, pstart, tile_e, tile_m, row_token);
  k_gather_x<<<MAX_ROWS / 2, 256, 0, stream>>>((const float4*)x, row_token,
                                               (us8*)xs);
  dim3 g(OUT_FEAT / BN, MAX_TILES);
  k_gemm<<<g, 256, 0, stream>>>(xs, w, pstart, tile_e, tile_m, row_token, out);
}